// Round 12
// baseline (883.641 us; speedup 1.0000x reference)
//
#include <hip/hip_runtime.h>

#define B_ 128
#define T_ 512
#define D_ 512
#define H_ 64
#define N3 192   // 3*H

#if __has_builtin(__builtin_amdgcn_rcpf)
#define RCP(x) __builtin_amdgcn_rcpf(x)
#else
#define RCP(x) (1.0f / (x))
#endif

typedef _Float16 h2v __attribute__((ext_vector_type(2)));

__device__ __forceinline__ float sigm_f(float x) {
  return RCP(1.0f + __expf(-x));
}
__device__ __forceinline__ float tanh_f(float x) {
  float e = __expf(-2.0f * fabsf(x));
  float t = (1.0f - e) * RCP(1.0f + e);
  return copysignf(t, x);
}

// 8-lane sum over lanes jj*8+g (g=0..7) entirely on the VALU via DPP:
// xor1 = quad_perm[1,0,3,2]=0xB1, xor2 = quad_perm[2,3,0,1]=0x4E,
// xor4 = row_half_mirror = 0x141.
template <int CTRL>
__device__ __forceinline__ float dpp_add(float v) {
  int t = __builtin_amdgcn_update_dpp(0, __float_as_int(v), CTRL, 0xF, 0xF, true);
  return v + __int_as_float(t);
}
__device__ __forceinline__ float red8(float v) {
  v = dpp_add<0xB1>(v);
  v = dpp_add<0x4E>(v);
  v = dpp_add<0x141>(v);
  return v;
}

// 8-elem dot: packed-f16 weights x packed-f16 h, f32 accumulation via
// v_dot2_f32_f16 (two chains for ILP).
__device__ __forceinline__ float dot8i4(int4 w, const h2v* h) {
  float s0 = __builtin_amdgcn_fdot2(__builtin_bit_cast(h2v, w.x), h[0], 0.0f, false);
  float s1 = __builtin_amdgcn_fdot2(__builtin_bit_cast(h2v, w.y), h[1], 0.0f, false);
  s0 = __builtin_amdgcn_fdot2(__builtin_bit_cast(h2v, w.z), h[2], s0, false);
  s1 = __builtin_amdgcn_fdot2(__builtin_bit_cast(h2v, w.w), h[3], s1, false);
  return s0 + s1;
}
__device__ __forceinline__ float dot8pk(const int* w, const h2v* h) {
  float s0 = __builtin_amdgcn_fdot2(__builtin_bit_cast(h2v, w[0]), h[0], 0.0f, false);
  float s1 = __builtin_amdgcn_fdot2(__builtin_bit_cast(h2v, w[1]), h[1], 0.0f, false);
  s0 = __builtin_amdgcn_fdot2(__builtin_bit_cast(h2v, w[2]), h[2], s0, false);
  s1 = __builtin_amdgcn_fdot2(__builtin_bit_cast(h2v, w[3]), h[3], s1, false);
  return s0 + s1;
}

#define KEEP(x) asm volatile("" : "+v"(x))

// ---------------- pass 1: gi0 = x @ W0ih^T + b0ih, plus act[t] flags ----------------
__global__ __launch_bounds__(256) void gemm_kernel(
    const float* __restrict__ x,     // [B,T,D]
    const float* __restrict__ w0ih,  // [N3,D]
    const float* __restrict__ b0ih,  // [N3]
    float* __restrict__ gi0,         // [B,Tc,N3]
    int* __restrict__ act,           // [T]
    int t0, int Tc) {
  __shared__ float Xs[64][33];
  __shared__ float Ws[64][33];
  __shared__ unsigned char sflag[64];

  int tid = threadIdx.x;
  int tpc = Tc >> 6;
  int b  = blockIdx.x / tpc;
  int tt = blockIdx.x % tpc;
  int c0 = blockIdx.y * 64;

  int tx = tid & 15, ty = tid >> 4;
  int r1  = tid >> 3;   // [0,32)
  int kc1 = tid & 7;    // [0,8)

  const float* xbase = x + ((size_t)b * T_ + t0 + tt * 64) * D_;
  const float* wbase = w0ih + (size_t)c0 * D_;

  float acc[4][4];
#pragma unroll
  for (int i = 0; i < 4; i++)
#pragma unroll
    for (int q = 0; q < 4; q++) acc[i][q] = 0.0f;

  bool f1 = false, f2 = false;

  for (int kt = 0; kt < D_ / 32; ++kt) {
    float4 va = *(const float4*)&xbase[(size_t)r1 * D_ + kt * 32 + kc1 * 4];
    float4 vb = *(const float4*)&xbase[(size_t)(r1 + 32) * D_ + kt * 32 + kc1 * 4];
    float4 wa = *(const float4*)&wbase[(size_t)r1 * D_ + kt * 32 + kc1 * 4];
    float4 wb = *(const float4*)&wbase[(size_t)(r1 + 32) * D_ + kt * 32 + kc1 * 4];
    f1 |= (va.x != 0.0f) | (va.y != 0.0f) | (va.z != 0.0f) | (va.w != 0.0f);
    f2 |= (vb.x != 0.0f) | (vb.y != 0.0f) | (vb.z != 0.0f) | (vb.w != 0.0f);
    __syncthreads();
    Xs[r1][kc1 * 4 + 0] = va.x; Xs[r1][kc1 * 4 + 1] = va.y;
    Xs[r1][kc1 * 4 + 2] = va.z; Xs[r1][kc1 * 4 + 3] = va.w;
    Xs[r1 + 32][kc1 * 4 + 0] = vb.x; Xs[r1 + 32][kc1 * 4 + 1] = vb.y;
    Xs[r1 + 32][kc1 * 4 + 2] = vb.z; Xs[r1 + 32][kc1 * 4 + 3] = vb.w;
    Ws[r1][kc1 * 4 + 0] = wa.x; Ws[r1][kc1 * 4 + 1] = wa.y;
    Ws[r1][kc1 * 4 + 2] = wa.z; Ws[r1][kc1 * 4 + 3] = wa.w;
    Ws[r1 + 32][kc1 * 4 + 0] = wb.x; Ws[r1 + 32][kc1 * 4 + 1] = wb.y;
    Ws[r1 + 32][kc1 * 4 + 2] = wb.z; Ws[r1 + 32][kc1 * 4 + 3] = wb.w;
    __syncthreads();
#pragma unroll
    for (int k = 0; k < 32; ++k) {
      float a_[4], b_[4];
#pragma unroll
      for (int i = 0; i < 4; i++) a_[i] = Xs[ty * 4 + i][k];
#pragma unroll
      for (int q = 0; q < 4; q++) b_[q] = Ws[tx * 4 + q][k];
#pragma unroll
      for (int i = 0; i < 4; i++)
#pragma unroll
        for (int q = 0; q < 4; q++) acc[i][q] = fmaf(a_[i], b_[q], acc[i][q]);
    }
  }

  float4 bias = *(const float4*)&b0ih[c0 + tx * 4];
#pragma unroll
  for (int i = 0; i < 4; i++) {
    int tloc = tt * 64 + ty * 4 + i;
    float4 o;
    o.x = acc[i][0] + bias.x;
    o.y = acc[i][1] + bias.y;
    o.z = acc[i][2] + bias.z;
    o.w = acc[i][3] + bias.w;
    *(float4*)&gi0[((size_t)b * Tc + tloc) * N3 + c0 + tx * 4] = o;
  }

  if (tid < 64) sflag[tid] = 0;
  __syncthreads();
  if (f1) sflag[r1] = 1;
  if (f2) sflag[r1 + 32] = 1;
  __syncthreads();
  if (tid < 64 && sflag[tid]) act[t0 + tt * 64 + tid] = 1;
}

// ---------------- pass 2: sequential scan, one WG (512 thr) per batch row ----------------
// Round-12: combine the two mechanisms that VERIFIED on hardware:
//  (a) hh-weights (W0hh/W1hh/W2hh) in f16-packed LDS, XOR-swizzled chunk
//      index (round-10 layout: measured SQ_LDS_BANK_CONFLICT = 0). 74KB.
//  (b) W1ih/W2ih + all 15 biases in registers: 24 f16x2 dwords + 15 floats
//      = 39 pinned regs, inside the ~63-value budget the allocator proved
//      willing to keep resident (round 9: VGPR=88, no spill). The 75-120
//      pinned-reg plans of rounds 2-11 ALWAYS spilled.
// All dots via v_dot2_f32_f16, f32 accumulation; state h0/h1/h2 stays f32
// (f16 rounding enters only as dot inputs -> no error compounding; absmax
// 0.00195 verified in round 11).
// Thread (jj = tid>>3, g = tid&7) owns cols [8g,8g+8) of rows {jj,jj+64,
// jj+128}. DPP reduce over g; 2 barriers/step.
// Hoisting discipline (round-5 race lesson): phase-0 may read only
// s_h16[0][cur] and s_h16[1][cur]; s_h16[2][cur]'s dot stays in layer 2.
__global__ __launch_bounds__(512, 2) void scan_kernel(
    const float* __restrict__ gi0,   // [B,Tc,N3]
    const float* __restrict__ w0hh, const float* __restrict__ w1ih,
    const float* __restrict__ w1hh, const float* __restrict__ w2ih,
    const float* __restrict__ w2hh,
    const float* __restrict__ b0hh, const float* __restrict__ b1ih,
    const float* __restrict__ b1hh, const float* __restrict__ b2ih,
    const float* __restrict__ b2hh,
    const int* __restrict__ act,     // [T]
    float* __restrict__ hstate,      // [3,B,H]
    float* __restrict__ out,         // [B,T,H]
    int t0, int Tc) {
  const int b   = blockIdx.x;
  const int tid = threadIdx.x;
  const int jj  = tid >> 3;   // [0,64) hidden unit
  const int g   = tid & 7;    // [0,8) segment

  // s_wh[m][row][chunk]: m 0=W0hh,1=W1hh,2=W2hh; row=[0,192); chunk=16B of
  // 8 f16 cols, physical chunk = logical ^ (row&7)  (bank swizzle).
  __shared__ __align__(16) int4 s_wh[3][192][8];      // 73728 B
  __shared__ __align__(16) _Float16 s_h16[3][2][H_];  // f16 h for dots
  __shared__ __align__(16) float s_out[32][H_];
  __shared__ int s_act[T_];

  // ---- one-time: f16-pack hh-weights into swizzled LDS ----
  {
    const float* wsrc[3] = {w0hh, w1hh, w2hh};
    for (int i = tid; i < 3 * 192 * 8; i += 512) {
      int m = i / 1536;
      int rem = i - m * 1536;
      int row = rem >> 3;        // [0,192)
      int c = rem & 7;           // logical 16B chunk (cols 8c..8c+8)
      const float* sp = wsrc[m] + (size_t)row * H_ + 8 * c;
      float4 lo = *(const float4*)sp;
      float4 hi = *(const float4*)(sp + 4);
      h2v p0 = {(_Float16)lo.x, (_Float16)lo.y};
      h2v p1 = {(_Float16)lo.z, (_Float16)lo.w};
      h2v p2 = {(_Float16)hi.x, (_Float16)hi.y};
      h2v p3 = {(_Float16)hi.z, (_Float16)hi.w};
      int4 pk;
      pk.x = __builtin_bit_cast(int, p0);
      pk.y = __builtin_bit_cast(int, p1);
      pk.z = __builtin_bit_cast(int, p2);
      pk.w = __builtin_bit_cast(int, p3);
      s_wh[m][row][c ^ (row & 7)] = pk;
    }
  }
  // this thread's swizzled chunk index (row&7 == jj&7 for its rows)
  const int cw = g ^ (jj & 7);

  // ---- register-resident: W1ih/W2ih f16x2 + all 15 biases ----
  int rpk[2][3][4];   // [mat: 0=W1ih, 1=W2ih][gate][dword]
  float bs[15];       // index m*3+r, m: 0=b0hh,1=b1ih,2=b1hh,3=b2ih,4=b2hh
  {
    const float* ip[2] = {w1ih, w2ih};
#pragma unroll
    for (int m = 0; m < 2; m++)
#pragma unroll
      for (int r = 0; r < 3; r++) {
        const float* src = ip[m] + (size_t)(jj + 64 * r) * H_ + 8 * g;
        float4 lo = *(const float4*)src;
        float4 hi = *(const float4*)(src + 4);
        h2v p0 = {(_Float16)lo.x, (_Float16)lo.y};
        h2v p1 = {(_Float16)lo.z, (_Float16)lo.w};
        h2v p2 = {(_Float16)hi.x, (_Float16)hi.y};
        h2v p3 = {(_Float16)hi.z, (_Float16)hi.w};
        rpk[m][r][0] = __builtin_bit_cast(int, p0);
        rpk[m][r][1] = __builtin_bit_cast(int, p1);
        rpk[m][r][2] = __builtin_bit_cast(int, p2);
        rpk[m][r][3] = __builtin_bit_cast(int, p3);
        KEEP(rpk[m][r][0]); KEEP(rpk[m][r][1]);
        KEEP(rpk[m][r][2]); KEEP(rpk[m][r][3]);
      }
    const float* bp[5] = {b0hh, b1ih, b1hh, b2ih, b2hh};
#pragma unroll
    for (int m = 0; m < 5; m++)
#pragma unroll
      for (int r = 0; r < 3; r++) {
        bs[m * 3 + r] = bp[m][jj + 64 * r];
        KEEP(bs[m * 3 + r]);
      }
  }

  // ---- h state: f32 registers (per jj, replicated over g) + f16 LDS copy ----
  float h0, h1, h2;
  if (t0 == 0) {
    h0 = 0.0f; h1 = 0.0f; h2 = 0.0f;
  } else {
    h0 = hstate[0 * B_ * H_ + b * H_ + jj];
    h1 = hstate[1 * B_ * H_ + b * H_ + jj];
    h2 = hstate[2 * B_ * H_ + b * H_ + jj];
  }
  if (tid < H_) {
    s_h16[0][0][tid] = (_Float16)((t0 == 0) ? 0.0f : hstate[0 * B_ * H_ + b * H_ + tid]);
    s_h16[1][0][tid] = (_Float16)((t0 == 0) ? 0.0f : hstate[1 * B_ * H_ + b * H_ + tid]);
    s_h16[2][0][tid] = (_Float16)((t0 == 0) ? 0.0f : hstate[2 * B_ * H_ + b * H_ + tid]);
  }
  for (int i = tid; i < Tc; i += 512) s_act[i] = act[t0 + i];
  __syncthreads();

  const float* gibase = gi0 + (size_t)b * Tc * N3;
  int cur = 0;
  float giR = gibase[jj], giZ = gibase[jj + 64], giN = gibase[jj + 128];

  // read 8 f16 h values (16B) for this thread's column segment
#define LOADH(dst, layer, par)                                          \
  h2v dst[4];                                                           \
  {                                                                     \
    float4 raw_ = *(const float4*)&s_h16[layer][par][8 * g];            \
    dst[0] = __builtin_bit_cast(h2v, raw_.x);                           \
    dst[1] = __builtin_bit_cast(h2v, raw_.y);                           \
    dst[2] = __builtin_bit_cast(h2v, raw_.z);                           \
    dst[3] = __builtin_bit_cast(h2v, raw_.w);                           \
  }

  for (int t = 0; t < Tc; ++t) {
    // prefetch next step's gi
    int tn = (t + 1 < Tc) ? t + 1 : t;
    const float* gin = gibase + (size_t)tn * N3;
    float nR = gin[jj], nZ = gin[jj + 64], nN = gin[jj + 128];

    const bool a = (s_act[t] != 0);

    // ---- phase 0: hh-dots for layers 0 and 1 (both barrier-protected) ----
    LOADH(ha, 0, cur);
    LOADH(hc, 1, cur);
    float dR = red8(dot8i4(s_wh[0][jj][cw], ha)) + bs[0];
    float dZ = red8(dot8i4(s_wh[0][jj + 64][cw], ha)) + bs[1];
    float dN = red8(dot8i4(s_wh[0][jj + 128][cw], ha)) + bs[2];
    float hR1 = red8(dot8i4(s_wh[1][jj][cw], hc)) + bs[6];
    float hZ1 = red8(dot8i4(s_wh[1][jj + 64][cw], hc)) + bs[7];
    float hN1 = red8(dot8i4(s_wh[1][jj + 128][cw], hc)) + bs[8];

    // ---- gate 0 ----
    {
      float r = sigm_f(giR + dR);
      float z = sigm_f(giZ + dZ);
      float n = tanh_f(giN + r * dN);
      float hn = (1.0f - z) * n + z * h0;
      h0 = a ? hn : h0;
    }
    if (g == 0) s_h16[0][cur ^ 1][jj] = (_Float16)h0;
    __syncthreads();

    // ---- layer 1: gi = W1ih @ h0new (registers) ; gate 1 ----
    {
      LOADH(he, 0, cur ^ 1);
      float iR = red8(dot8pk(rpk[0][0], he)) + bs[3];
      float iZ = red8(dot8pk(rpk[0][1], he)) + bs[4];
      float iN = red8(dot8pk(rpk[0][2], he)) + bs[5];
      float r = sigm_f(iR + hR1);
      float z = sigm_f(iZ + hZ1);
      float n = tanh_f(iN + r * hN1);
      float hn = (1.0f - z) * n + z * h1;
      h1 = a ? hn : h1;
    }
    if (g == 0) s_h16[1][cur ^ 1][jj] = (_Float16)h1;
    __syncthreads();

    // ---- layer 2: gi = W2ih @ h1new (registers) ; gh = W2hh @ h2 (LDS;
    //      safe here: two barriers since s_h16[2][cur] was written) ----
    {
      LOADH(hf, 1, cur ^ 1);
      LOADH(hg, 2, cur);
      float jR = red8(dot8pk(rpk[1][0], hf)) + bs[9];
      float jZ = red8(dot8pk(rpk[1][1], hf)) + bs[10];
      float jN = red8(dot8pk(rpk[1][2], hf)) + bs[11];
      float kR = red8(dot8i4(s_wh[2][jj][cw], hg)) + bs[12];
      float kZ = red8(dot8i4(s_wh[2][jj + 64][cw], hg)) + bs[13];
      float kN = red8(dot8i4(s_wh[2][jj + 128][cw], hg)) + bs[14];
      float r = sigm_f(jR + kR);
      float z = sigm_f(jZ + kZ);
      float n = tanh_f(jN + r * kN);
      float hn = (1.0f - z) * n + z * h2;
      h2 = a ? hn : h2;
    }
    if (g == 0) {
      s_h16[2][cur ^ 1][jj] = (_Float16)h2;
      s_out[t & 31][jj] = a ? h2 : 0.0f;
    }
    // no barrier needed: s_h16[2][cur^1] is next read in layer 2 of step t+1
    // (behind two barriers); s_h16[0/1] writes are barrier-protected above.
    cur ^= 1;
    giR = nR; giZ = nZ; giN = nN;

    if ((t & 31) == 31) {            // coalesced output flush (Tc % 32 == 0)
      __syncthreads();
      int row = tid >> 4, c4 = (tid & 15) * 4;
      *(float4*)&out[((size_t)b * T_ + t0 + (t - 31) + row) * H_ + c4] =
          *(const float4*)&s_out[row][c4];
      // next s_out write happens after the next step's barriers -> safe
    }
  }
#undef LOADH

  if (g == 0) {
    hstate[0 * B_ * H_ + b * H_ + jj] = h0;
    hstate[1 * B_ * H_ + b * H_ + jj] = h1;
    hstate[2 * B_ * H_ + b * H_ + jj] = h2;
  }
}

extern "C" void kernel_launch(void* const* d_in, const int* in_sizes, int n_in,
                              void* d_out, int out_size, void* d_ws, size_t ws_size,
                              hipStream_t stream) {
  const float* x    = (const float*)d_in[0];
  const float* w0ih = (const float*)d_in[1];
  const float* w0hh = (const float*)d_in[2];
  const float* b0ih = (const float*)d_in[3];
  const float* b0hh = (const float*)d_in[4];
  const float* w1ih = (const float*)d_in[5];
  const float* w1hh = (const float*)d_in[6];
  const float* b1ih = (const float*)d_in[7];
  const float* b1hh = (const float*)d_in[8];
  const float* w2ih = (const float*)d_in[9];
  const float* w2hh = (const float*)d_in[10];
  const float* b2ih = (const float*)d_in[11];
  const float* b2hh = (const float*)d_in[12];
  float* out = (float*)d_out;

  char* p = (char*)d_ws;
  int* act      = (int*)p;    p += 4096;
  float* hstate = (float*)p;  p += (size_t)3 * B_ * H_ * 4;
  size_t fixed = (size_t)(p - (char*)d_ws);

  int Tc = T_;
  while (Tc > 64 && fixed + (size_t)B_ * Tc * N3 * 4 > ws_size) Tc >>= 1;
  float* gi0 = (float*)p;

  hipMemsetAsync(act, 0, T_ * sizeof(int), stream);
  for (int t0 = 0; t0 < T_; t0 += Tc) {
    gemm_kernel<<<dim3(B_ * (Tc / 64), 3), 256, 0, stream>>>(
        x, w0ih, b0ih, gi0, act, t0, Tc);
    scan_kernel<<<B_, 512, 0, stream>>>(
        gi0, w0hh, w1ih, w1hh, w2ih, w2hh,
        b0hh, b1ih, b1hh, b2ih, b2hh, act, hstate, out, t0, Tc);
  }
}